// Round 1
// baseline (224.186 us; speedup 1.0000x reference)
//
#include <hip/hip_runtime.h>

// PolynomialRegression: out[b][o] = W[o][0] + sum_i W[o][1+i]*x[b][i]
//                                  + sum_{i<=j} W[o][257+idx(i,j)]*x[b][i]*x[b][j]
// idx(i,j) = i*256 - i*(i-1)/2 + (j-i)   (np.triu_indices order)
// B=4096, D=256, NF=33153, out (4096,10) fp32.

#define DD 256
#define NF 33153
#define ROWS_PER_BLOCK 64
#define KBLOCKS 8
#define TPB 256
#define LDS_STRIDE 257   // +1 pad: bank = (lane + j) % 32 -> 2-way (free)

__global__ __launch_bounds__(TPB, 2)
void PolynomialRegression_75385265979710_kernel(const float* __restrict__ x,
                                                const float* __restrict__ W,
                                                float* __restrict__ out) {
    __shared__ float smem[ROWS_PER_BLOCK * LDS_STRIDE];
    const int tid  = threadIdx.x;
    const int lane = tid & 63;
    const int wave = tid >> 6;
    const int rowbase = blockIdx.x * ROWS_PER_BLOCK;
    const int s = blockIdx.y * 4 + wave;   // slice 0..31: handles i == s (mod 32)

    // Coalesced stage of the 64-row x tile into LDS.
    for (int idx = tid; idx < ROWS_PER_BLOCK * DD; idx += TPB) {
        int r = idx >> 8, c = idx & 255;
        smem[r * LDS_STRIDE + c] = x[(rowbase + r) * DD + c];
    }
    __syncthreads();

    const float* xt = &smem[lane * LDS_STRIDE];  // this thread's row
    float acc[10];
#pragma unroll
    for (int o = 0; o < 10; ++o) acc[o] = 0.f;

    // Quadratic terms: for each owned i, inner_o = sum_{j>=i} W2[o][i,j]*x_j,
    // then acc_o += x_i * inner_o.
    for (int i = s; i < DD; i += 32) {
        float xi = xt[i];
        float inner[10];
#pragma unroll
        for (int o = 0; o < 10; ++o) inner[o] = 0.f;
        int fbase = 1 + DD + i * DD - (i * (i - 1)) / 2 - i;  // f = fbase + j
        fbase = __builtin_amdgcn_readfirstlane(fbase);        // force s_load path for W
#pragma unroll 4
        for (int j = i; j < DD; ++j) {
            float xj = xt[j];
            int f = fbase + j;
#pragma unroll
            for (int o = 0; o < 10; ++o)
                inner[o] = fmaf(W[o * NF + f], xj, inner[o]);
        }
#pragma unroll
        for (int o = 0; o < 10; ++o) acc[o] = fmaf(xi, inner[o], acc[o]);
    }

    // Bias + linear terms on the smallest slice (s=31 has the fewest pairs).
    if (s == 31) {
        float inner[10];
#pragma unroll
        for (int o = 0; o < 10; ++o) inner[o] = W[o * NF];  // bias
#pragma unroll 4
        for (int j = 0; j < DD; ++j) {
            float xj = xt[j];
#pragma unroll
            for (int o = 0; o < 10; ++o)
                inner[o] = fmaf(W[o * NF + 1 + j], xj, inner[o]);
        }
#pragma unroll
        for (int o = 0; o < 10; ++o) acc[o] += inner[o];
    }

    __syncthreads();  // x tile dead; reuse LDS for the 4-wave reduction
    float* red = smem;  // [wave][lane][o] : 4*64*10 = 2560 floats
#pragma unroll
    for (int o = 0; o < 10; ++o) red[(wave * 64 + lane) * 10 + o] = acc[o];
    __syncthreads();

    for (int e = tid; e < ROWS_PER_BLOCK * 10; e += TPB) {
        int r = e / 10, o = e % 10;
        float v = red[(0 * 64 + r) * 10 + o] + red[(1 * 64 + r) * 10 + o] +
                  red[(2 * 64 + r) * 10 + o] + red[(3 * 64 + r) * 10 + o];
        atomicAdd(&out[(rowbase + r) * 10 + o], v);
    }
}

extern "C" void kernel_launch(void* const* d_in, const int* in_sizes, int n_in,
                              void* d_out, int out_size, void* d_ws, size_t ws_size,
                              hipStream_t stream) {
    const float* x = (const float*)d_in[0];   // (4096, 256)
    const float* W = (const float*)d_in[1];   // (10, 33153)
    float* out = (float*)d_out;               // (4096, 10)

    hipMemsetAsync(out, 0, (size_t)out_size * sizeof(float), stream);

    dim3 grid(4096 / ROWS_PER_BLOCK, KBLOCKS);
    PolynomialRegression_75385265979710_kernel<<<grid, TPB, 0, stream>>>(x, W, out);
}

// Round 2
// 79.017 us; speedup vs baseline: 2.8372x; 2.8372x over previous
//
#include <hip/hip_runtime.h>

// PolynomialRegression via bf16 MFMA:
//   y[b][o] = bias_o + sum_i x[b][i] * ( (U_o x[b])_i + W1[o][i] )
// where U_o[i][j] = W[o][257 + i*256 - i(i-1)/2 + (j-i)] for j>=i, else 0.
// T = X_bf16 @ G^T  (G rows = U_o rows, 2560x256) -- 4096x2560x256 bf16 GEMM,
// fp32 accumulate, fused dot-reduce epilogue (T never materialized).

#define DD 256
#define NF 33153
#define BM 64
#define BK 64
#define TPB 256
#define APAD 72   // 64 + 8 bf16: b128 LDS reads alias 2-way (free)

typedef __attribute__((ext_vector_type(8))) short short8;
typedef __attribute__((ext_vector_type(4))) float floatx4;
typedef __attribute__((ext_vector_type(4))) unsigned short ushortx4;

__device__ inline unsigned short f2bf(float f) {
    unsigned u = __builtin_bit_cast(unsigned, f);
    return (unsigned short)((u + 0x7FFFu + ((u >> 16) & 1u)) >> 16);  // RNE
}

// --- prep 1: X fp32 -> bf16 (1M elems, 4/thread) ---
__global__ void xconv_kernel(const float* __restrict__ x, unsigned short* __restrict__ xb) {
    int i = (blockIdx.x * TPB + threadIdx.x) * 4;
    float4 v = *(const float4*)&x[i];
    ushortx4 r;
    r.x = f2bf(v.x); r.y = f2bf(v.y); r.z = f2bf(v.z); r.w = f2bf(v.w);
    *(ushortx4*)&xb[i] = r;
}

// --- prep 2: scatter W2 into dense upper-triangular G (2560x256 bf16) ---
__global__ void gbuild_kernel(const float* __restrict__ W, unsigned short* __restrict__ G) {
    int oi = blockIdx.x;            // o*256 + i
    int o = oi >> 8, i = oi & 255;
    int j = threadIdx.x;
    int base = o * NF + 257 + i * DD - (i * (i - 1)) / 2 - i;   // + j for j>=i
    float v = (j >= i) ? W[base + j] : 0.f;
    G[oi * DD + j] = f2bf(v);
}

// --- main: fused GEMM + quadratic-form epilogue ---
__global__ __launch_bounds__(TPB)
void PolynomialRegression_75385265979710_kernel(const float* __restrict__ x,
                                                const float* __restrict__ W,
                                                const unsigned short* __restrict__ Xbf,
                                                const unsigned short* __restrict__ G,
                                                float* __restrict__ out) {
    __shared__ __align__(16) unsigned short As[BM * APAD];  // 9216 B
    __shared__ float red[4 * BM];                           // 1 KB

    const int tid  = threadIdx.x;
    const int lane = tid & 63;
    const int wave = tid >> 6;
    const int ln   = lane & 15;
    const int quad = lane >> 4;
    const int rowbase = blockIdx.x * BM;
    const int o  = blockIdx.y;
    const int wn0 = wave * 64;     // this wave's i-range: [wn0, wn0+64)

    floatx4 acc[4][4];             // [m_tile][n_tile], 64 VGPRs
#pragma unroll
    for (int mt = 0; mt < 4; ++mt)
#pragma unroll
        for (int nt = 0; nt < 4; ++nt) acc[mt][nt] = (floatx4)0.f;

    for (int kt = 0; kt < 4; ++kt) {
        const int k0 = kt * BK;
        // stage A-tile (64 rows x 64 k, bf16) into LDS; 2 x short8 per thread
#pragma unroll
        for (int p = 0; p < 2; ++p) {
            int c = p * TPB + tid;            // 0..511
            int r = c >> 3, col = (c & 7) * 8;
            *(short8*)&As[r * APAD + col] =
                *(const short8*)&Xbf[(rowbase + r) * DD + k0 + col];
        }
        __syncthreads();
#pragma unroll
        for (int ks = 0; ks < 2; ++ks) {
            const int kk = k0 + ks * 32 + quad * 8;
            short8 b[4], a[4];
#pragma unroll
            for (int nt = 0; nt < 4; ++nt)     // B-frags straight from L2 (G is hot)
                b[nt] = *(const short8*)&G[(o * DD + wn0 + nt * 16 + ln) * DD + kk];
#pragma unroll
            for (int mt = 0; mt < 4; ++mt)
                a[mt] = *(const short8*)&As[(mt * 16 + ln) * APAD + ks * 32 + quad * 8];
#pragma unroll
            for (int mt = 0; mt < 4; ++mt)
#pragma unroll
                for (int nt = 0; nt < 4; ++nt)
                    acc[mt][nt] = __builtin_amdgcn_mfma_f32_16x16x32_bf16(
                        a[mt], b[nt], acc[mt][nt], 0, 0, 0);
        }
        __syncthreads();
    }

    // Epilogue: y_part[m] = sum_{i in wave's range} x_f32[m][i] * (T[m][i] + W1[o][i])
    float wl[4];
#pragma unroll
    for (int nt = 0; nt < 4; ++nt)
        wl[nt] = W[o * NF + 1 + wn0 + nt * 16 + ln];

#pragma unroll
    for (int mt = 0; mt < 4; ++mt) {
#pragma unroll
        for (int r = 0; r < 4; ++r) {
            const int m = mt * 16 + quad * 4 + r;   // C/D layout: row=quad*4+reg, col=ln
            float p = 0.f;
#pragma unroll
            for (int nt = 0; nt < 4; ++nt) {
                float xv = x[(rowbase + m) * DD + wn0 + nt * 16 + ln];
                p = fmaf(xv, acc[mt][nt][r] + wl[nt], p);
            }
            p += __shfl_xor(p, 1);
            p += __shfl_xor(p, 2);
            p += __shfl_xor(p, 4);
            p += __shfl_xor(p, 8);
            if (ln == 0) red[wave * BM + m] = p;
        }
    }
    __syncthreads();

    if (tid < BM) {
        const int m = tid;
        float s = red[m] + red[BM + m] + red[2 * BM + m] + red[3 * BM + m] + W[o * NF];
        out[(rowbase + m) * 10 + o] = s;
    }
}

extern "C" void kernel_launch(void* const* d_in, const int* in_sizes, int n_in,
                              void* d_out, int out_size, void* d_ws, size_t ws_size,
                              hipStream_t stream) {
    const float* x = (const float*)d_in[0];   // (4096, 256)
    const float* W = (const float*)d_in[1];   // (10, 33153)
    float* out = (float*)d_out;               // (4096, 10)

    unsigned short* Xbf = (unsigned short*)d_ws;            // 2 MB
    unsigned short* G   = Xbf + 4096 * DD;                  // 1.31 MB

    xconv_kernel<<<4096 * DD / (4 * TPB), TPB, 0, stream>>>(x, Xbf);
    gbuild_kernel<<<10 * DD, TPB, 0, stream>>>(W, G);

    dim3 grid(4096 / BM, 10);
    PolynomialRegression_75385265979710_kernel<<<grid, TPB, 0, stream>>>(x, W, Xbf, G, out);
}